// Round 4
// baseline (3327.132 us; speedup 1.0000x reference)
//
#include <hip/hip_runtime.h>
#include <cstdint>
#include <cstddef>

#define BATCH 256
#define SEQ   512
#define HID   512
#define VOCAB 128

#define BT    16               // batch rows per block
#define HSTR  520              // h-buffer row stride in shorts (1040 B)

typedef __attribute__((ext_vector_type(8))) short bf16x8;
typedef __attribute__((ext_vector_type(4))) float f32x4;

static __device__ __forceinline__ uint16_t f2bf(float f) {
  uint32_t x = __float_as_uint(f);
  return (uint16_t)((x + 0x7fffu + ((x >> 16) & 1u)) >> 16);
}
static __device__ __forceinline__ float bf2f(uint16_t u) {
  return __uint_as_float(((uint32_t)u) << 16);
}
// tanh(z) = 1 - 2/(e^{2z}+1); saturates correctly at +/-inf
static __device__ __forceinline__ float fast_tanh(float z) {
  float e = __expf(2.f * z);
  return 1.f - 2.f * __builtin_amdgcn_rcpf(e + 1.f);
}

// E[v][j] = sum_k emb[v][k]*W_ih[k][j] + b_ih[j] + b_hh[j]
__global__ __launch_bounds__(512) void eproj_kernel(const float* __restrict__ emb,
                                                    const float* __restrict__ W_ih,
                                                    const float* __restrict__ b_ih,
                                                    const float* __restrict__ b_hh,
                                                    float* __restrict__ E) {
  __shared__ float es[8][64];
  const int j = threadIdx.x;
  const int v0 = blockIdx.x * 8;
  float acc[8];
#pragma unroll
  for (int v = 0; v < 8; ++v) acc[v] = 0.f;
  for (int k0 = 0; k0 < HID; k0 += 64) {
    __syncthreads();
    es[j >> 6][j & 63] = emb[(size_t)(v0 + (j >> 6)) * HID + k0 + (j & 63)];
    __syncthreads();
#pragma unroll 8
    for (int kk = 0; kk < 64; ++kk) {
      const float w = W_ih[(size_t)(k0 + kk) * HID + j];
#pragma unroll
      for (int v = 0; v < 8; ++v) acc[v] += es[v][kk] * w;
    }
  }
  const float bias = b_ih[j] + b_hh[j];
#pragma unroll
  for (int v = 0; v < 8; ++v) E[(size_t)(v0 + v) * HID + j] = acc[v] + bias;
}

// Pack [W_hh | W_ho] (512 x 640) into bf16 MFMA B-fragments (layout verified r1-r3).
// Fragment f = nt*16+kt: lane l holds 8 bf16 = B[k = kt*32 + (l>>4)*8 + i][n = nt*16 + (l&15)]
__global__ void pack_kernel(const float* __restrict__ W_hh,
                            const float* __restrict__ W_ho,
                            uint32_t* __restrict__ Wf) {
  const int f = blockIdx.x;            // 0..639
  const int nt = f >> 4, kt = f & 15;
  const int lane = threadIdx.x;
  const int q = lane >> 4, nn = lane & 15;
  const int n = nt * 16 + nn;
  const int k0 = kt * 32 + q * 8;
  uint32_t w[4];
#pragma unroll
  for (int p = 0; p < 4; ++p) {
    const int k = k0 + 2 * p;
    float f0, f1;
    if (n < HID) { f0 = W_hh[(size_t)k * HID + n];           f1 = W_hh[(size_t)(k + 1) * HID + n]; }
    else         { f0 = W_ho[(size_t)k * VOCAB + (n - HID)]; f1 = W_ho[(size_t)(k + 1) * VOCAB + (n - HID)]; }
    w[p] = (uint32_t)f2bf(f0) | ((uint32_t)f2bf(f1) << 16);
  }
  uint4 val; val.x = w[0]; val.y = w[1]; val.z = w[2]; val.w = w[3];
  ((uint4*)Wf)[(size_t)f * 64 + lane] = val;
}

// Recurrence: h_t = tanh(E[x_t] + h_{t-1} @ W_hh), y deferred to ygemm.
// 16 blocks x 512 threads (8 waves). Wave w owns n-tiles w*4..w*4+3, ALL
// register-resident in AGPRs (256/wave, forced via "+a" pins). h double-buffered
// in LDS -> single barrier per step. No inter-block sync.
__global__ __launch_bounds__(512)
void rnn_kernel(const int* __restrict__ x,
                const float* __restrict__ E,
                const uint4* __restrict__ Wf,
                uint16_t* __restrict__ Hall) {
  __shared__ uint16_t hbuf[2][BT][HSTR];   // 33280 B

  const int tid = threadIdx.x;
  const int wave = tid >> 6, lane = tid & 63;
  const int q = lane >> 4, nn = lane & 15;
  const int r0 = blockIdx.x * BT;

  // 4 weight strips per wave, pinned in AGPRs so loads cannot sink into the loop
  bf16x8 wreg[4][16];
  {
    const uint4* wb = Wf + lane;
#pragma unroll
    for (int j = 0; j < 4; ++j)
#pragma unroll
      for (int kt = 0; kt < 16; ++kt)
        wreg[j][kt] = __builtin_bit_cast(bf16x8, wb[(size_t)((wave * 4 + j) * 16 + kt) * 64]);
  }
#pragma unroll
  for (int j = 0; j < 4; ++j)
#pragma unroll
    for (int kt = 0; kt < 16; ++kt)
      asm volatile("" : "+a"(wreg[j][kt]));

  // token prefetch for t=0
  int tokc[4];
#pragma unroll
  for (int r = 0; r < 4; ++r) tokc[r] = x[(size_t)(r0 + q * 4 + r) * SEQ + 0];

  for (int t = 0; t < SEQ; ++t) {
    // next step's tokens (independent; issued early)
    int tokn[4];
    const int tn = (t + 1 < SEQ) ? t + 1 : t;
#pragma unroll
    for (int r = 0; r < 4; ++r) tokn[r] = x[(size_t)(r0 + q * 4 + r) * SEQ + tn];

    // E rows for this step's epilogue (long slack: consumed after the MFMAs)
    float ev[4][4];
#pragma unroll
    for (int j = 0; j < 4; ++j)
#pragma unroll
      for (int r = 0; r < 4; ++r)
        ev[j][r] = E[(size_t)tokc[r] * HID + wave * 64 + j * 16 + nn];

    f32x4 acc[4];
#pragma unroll
    for (int j = 0; j < 4; ++j) acc[j] = f32x4{0.f, 0.f, 0.f, 0.f};

    if (t > 0) {
      const uint16_t* hr = &hbuf[(t - 1) & 1][0][0];
#pragma unroll
      for (int kt = 0; kt < 16; ++kt) {
        const bf16x8 a = __builtin_bit_cast(bf16x8,
            *(const uint4*)&hr[nn * HSTR + kt * 32 + q * 8]);
        acc[0] = __builtin_amdgcn_mfma_f32_16x16x32_bf16(a, wreg[0][kt], acc[0], 0, 0, 0);
        acc[1] = __builtin_amdgcn_mfma_f32_16x16x32_bf16(a, wreg[1][kt], acc[1], 0, 0, 0);
        acc[2] = __builtin_amdgcn_mfma_f32_16x16x32_bf16(a, wreg[2][kt], acc[2], 0, 0, 0);
        acc[3] = __builtin_amdgcn_mfma_f32_16x16x32_bf16(a, wreg[3][kt], acc[3], 0, 0, 0);
      }
    }

    // epilogue: h = tanh(z + ev) into the OTHER buffer (no barrier needed before)
    uint16_t* hw = &hbuf[t & 1][0][0];
#pragma unroll
    for (int j = 0; j < 4; ++j) {
      const int col = wave * 64 + j * 16 + nn;
#pragma unroll
      for (int r = 0; r < 4; ++r) {
        const int m = q * 4 + r;
        const uint16_t hb = f2bf(fast_tanh(acc[j][r] + ev[j][r]));
        hw[m * HSTR + col] = hb;
        Hall[((size_t)(r0 + m) * SEQ + t) * HID + col] = hb;
      }
    }
    __syncthreads();   // single barrier: publishes hbuf[t&1]; guards 2-cycle reuse

#pragma unroll
    for (int r = 0; r < 4; ++r) tokc[r] = tokn[r];
  }
}

// Y[b,s,:] = h_{b,s} @ W_ho + b_o over all 131072 rows — fully parallel.
__global__ __launch_bounds__(256)
void ygemm_kernel(const uint16_t* __restrict__ Hall,
                  const uint4* __restrict__ Wf,
                  const float* __restrict__ b_o,
                  float* __restrict__ out) {
  const int tid = threadIdx.x;
  const int wave = tid >> 6, lane = tid & 63;
  const int q = lane >> 4, nn = lane & 15;
  const size_t row0 = (size_t)blockIdx.x * 64 + (size_t)wave * 16;
  f32x4 acc[8];
#pragma unroll
  for (int i = 0; i < 8; ++i) acc[i] = f32x4{0.f, 0.f, 0.f, 0.f};
  const uint16_t* ha = Hall + (row0 + nn) * HID + q * 8;
  const uint4* wb = Wf + (size_t)(32 * 16) * 64 + lane;   // W_ho fragments: nt 32..39
#pragma unroll 4
  for (int kt = 0; kt < 16; ++kt) {
    const bf16x8 a = __builtin_bit_cast(bf16x8, *(const uint4*)(ha + kt * 32));
#pragma unroll
    for (int nt = 0; nt < 8; ++nt) {
      const bf16x8 b = __builtin_bit_cast(bf16x8, wb[(size_t)(nt * 16 + kt) * 64]);
      acc[nt] = __builtin_amdgcn_mfma_f32_16x16x32_bf16(a, b, acc[nt], 0, 0, 0);
    }
  }
#pragma unroll
  for (int nt = 0; nt < 8; ++nt) {
    const float bo = b_o[nt * 16 + nn];
#pragma unroll
    for (int r = 0; r < 4; ++r)
      out[(row0 + q * 4 + r) * VOCAB + nt * 16 + nn] = acc[nt][r] + bo;
  }
}

__global__ __launch_bounds__(512)
void ht_kernel(const uint16_t* __restrict__ Hall, float* __restrict__ outH) {
  const int i = blockIdx.x * 512 + threadIdx.x;
  const int b = i >> 9, h = i & (HID - 1);
  outH[i] = bf2f(Hall[((size_t)b * SEQ + (SEQ - 1)) * HID + h]);
}

extern "C" void kernel_launch(void* const* d_in, const int* in_sizes, int n_in,
                              void* d_out, int out_size, void* d_ws, size_t ws_size,
                              hipStream_t stream) {
  const int*   x    = (const int*)d_in[0];
  const float* emb  = (const float*)d_in[1];
  const float* W_ih = (const float*)d_in[2];
  const float* b_ih = (const float*)d_in[3];
  const float* W_hh = (const float*)d_in[4];
  const float* b_hh = (const float*)d_in[5];
  const float* W_ho = (const float*)d_in[6];
  const float* b_o  = (const float*)d_in[7];
  float* out = (float*)d_out;

  char* ws = (char*)d_ws;
  float*    E    = (float*)ws;                              // 256 KB
  uint32_t* Wf   = (uint32_t*)(ws + (256 << 10));           // 640 KB
  uint16_t* Hall = (uint16_t*)(ws + (1 << 20));             // 128 MB

  eproj_kernel<<<VOCAB / 8, 512, 0, stream>>>(emb, W_ih, b_ih, b_hh, E);
  pack_kernel<<<640, 64, 0, stream>>>(W_hh, W_ho, Wf);
  rnn_kernel<<<16, 512, 0, stream>>>(x, E, (const uint4*)Wf, Hall);
  ygemm_kernel<<<(BATCH * SEQ) / 64, 256, 0, stream>>>(Hall, (const uint4*)Wf, b_o, out);
  ht_kernel<<<BATCH * HID / 512, 512, 0, stream>>>(Hall, out + (size_t)BATCH * SEQ * VOCAB);
}

// Round 5
// 1904.584 us; speedup vs baseline: 1.7469x; 1.7469x over previous
//
#include <hip/hip_runtime.h>
#include <cstdint>
#include <cstddef>

#define BATCH 256
#define SEQ   512
#define HID   512
#define VOCAB 128

#define BT    16               // batch rows per block
#define HSTR  520              // h-buffer row stride in shorts (1040 B)
#define LWF_BYTES  131072      // 8 strips * 16 frags * 1024 B
#define HBUF_BYTES (BT * HSTR * 2)            // 16640
#define SMEM_BYTES (LWF_BYTES + HBUF_BYTES)   // 147712

typedef __attribute__((ext_vector_type(8))) short bf16x8;
typedef __attribute__((ext_vector_type(4))) float f32x4;

static __device__ __forceinline__ uint16_t f2bf(float f) {
  uint32_t x = __float_as_uint(f);
  return (uint16_t)((x + 0x7fffu + ((x >> 16) & 1u)) >> 16);
}
static __device__ __forceinline__ float bf2f(uint16_t u) {
  return __uint_as_float(((uint32_t)u) << 16);
}
// tanh(z) = 1 - 2/(e^{2z}+1); saturates correctly at +/-inf
static __device__ __forceinline__ float fast_tanh(float z) {
  float e = __expf(2.f * z);
  return 1.f - 2.f * __builtin_amdgcn_rcpf(e + 1.f);
}

// E[v][j] = sum_k emb[v][k]*W_ih[k][j] + b_ih[j] + b_hh[j]
__global__ __launch_bounds__(512) void eproj_kernel(const float* __restrict__ emb,
                                                    const float* __restrict__ W_ih,
                                                    const float* __restrict__ b_ih,
                                                    const float* __restrict__ b_hh,
                                                    float* __restrict__ E) {
  __shared__ float es[8][64];
  const int j = threadIdx.x;
  const int v0 = blockIdx.x * 8;
  float acc[8];
#pragma unroll
  for (int v = 0; v < 8; ++v) acc[v] = 0.f;
  for (int k0 = 0; k0 < HID; k0 += 64) {
    __syncthreads();
    es[j >> 6][j & 63] = emb[(size_t)(v0 + (j >> 6)) * HID + k0 + (j & 63)];
    __syncthreads();
#pragma unroll 8
    for (int kk = 0; kk < 64; ++kk) {
      const float w = W_ih[(size_t)(k0 + kk) * HID + j];
#pragma unroll
      for (int v = 0; v < 8; ++v) acc[v] += es[v][kk] * w;
    }
  }
  const float bias = b_ih[j] + b_hh[j];
#pragma unroll
  for (int v = 0; v < 8; ++v) E[(size_t)(v0 + v) * HID + j] = acc[v] + bias;
}

// Pack [W_hh | W_ho] (512 x 640) into bf16 MFMA B-fragments (layout verified r1-r4).
// Fragment f = nt*16+kt: lane l holds 8 bf16 = B[k = kt*32 + (l>>4)*8 + i][n = nt*16 + (l&15)]
__global__ void pack_kernel(const float* __restrict__ W_hh,
                            const float* __restrict__ W_ho,
                            uint32_t* __restrict__ Wf) {
  const int f = blockIdx.x;            // 0..639
  const int nt = f >> 4, kt = f & 15;
  const int lane = threadIdx.x;
  const int q = lane >> 4, nn = lane & 15;
  const int n = nt * 16 + nn;
  const int k0 = kt * 32 + q * 8;
  uint32_t w[4];
#pragma unroll
  for (int p = 0; p < 4; ++p) {
    const int k = k0 + 2 * p;
    float f0, f1;
    if (n < HID) { f0 = W_hh[(size_t)k * HID + n];           f1 = W_hh[(size_t)(k + 1) * HID + n]; }
    else         { f0 = W_ho[(size_t)k * VOCAB + (n - HID)]; f1 = W_ho[(size_t)(k + 1) * VOCAB + (n - HID)]; }
    w[p] = (uint32_t)f2bf(f0) | ((uint32_t)f2bf(f1) << 16);
  }
  uint4 val; val.x = w[0]; val.y = w[1]; val.z = w[2]; val.w = w[3];
  ((uint4*)Wf)[(size_t)f * 64 + lane] = val;
}

// Recurrence: h_t = tanh(E[x_t] + h_{t-1} @ W_hh), y deferred to ygemm.
// 16 blocks x 256 threads (4 waves, 1 wave/SIMD -> 512-reg budget/wave).
// Wave w owns n-tiles w*8..w*8+7: 6 strips in AGPR (384 regs, zero spills),
// 2 strips in LDS. h single-buffered in LDS; 2 barriers/step. No inter-block sync.
__global__ __launch_bounds__(256, 1)
void rnn_kernel(const int* __restrict__ x,
                const float* __restrict__ E,
                const uint4* __restrict__ Wf,
                uint16_t* __restrict__ Hall) {
  extern __shared__ char smem[];
  uint4*    lwf  = (uint4*)smem;                    // 8 strips = 128 KB
  uint16_t* hbuf = (uint16_t*)(smem + LWF_BYTES);   // [BT][HSTR]

  const int tid = threadIdx.x;
  const int wave = tid >> 6, lane = tid & 63;
  const int q = lane >> 4, nn = lane & 15;
  const int r0 = blockIdx.x * BT;

  // stage the 8 LDS strips: strip s (s=0..7) = n-tile (s>>1)*8 + 6 + (s&1)
  for (int i = tid; i < 8192; i += 256) {
    const int s = i >> 10, kt = (i >> 6) & 15, ln = i & 63;
    const int nt = (s >> 1) * 8 + 6 + (s & 1);
    lwf[i] = Wf[(size_t)(nt * 16 + kt) * 64 + ln];
  }

  // 6 weight strips per wave in AGPRs (384 regs), pinned so loads cannot sink
  bf16x8 wreg[6][16];
  {
    const uint4* wb = Wf + lane;
#pragma unroll
    for (int j = 0; j < 6; ++j)
#pragma unroll
      for (int kt = 0; kt < 16; ++kt)
        wreg[j][kt] = __builtin_bit_cast(bf16x8, wb[(size_t)((wave * 8 + j) * 16 + kt) * 64]);
  }
#pragma unroll
  for (int j = 0; j < 6; ++j)
#pragma unroll
    for (int kt = 0; kt < 16; ++kt)
      asm volatile("" : "+a"(wreg[j][kt]));

  const uint4* lw0 = lwf + (size_t)((wave * 2 + 0) * 16) * 64 + lane;
  const uint4* lw1 = lwf + (size_t)((wave * 2 + 1) * 16) * 64 + lane;

  __syncthreads();

  // token prefetch for t=0
  int tokc[4];
#pragma unroll
  for (int r = 0; r < 4; ++r) tokc[r] = x[(size_t)(r0 + q * 4 + r) * SEQ + 0];

  for (int t = 0; t < SEQ; ++t) {
    // next step's tokens (independent; issued early)
    int tokn[4];
    const int tn = (t + 1 < SEQ) ? t + 1 : t;
#pragma unroll
    for (int r = 0; r < 4; ++r) tokn[r] = x[(size_t)(r0 + q * 4 + r) * SEQ + tn];

    // E rows for this step's epilogue — issued before the K-loop, consumed after:
    // the whole MFMA loop hides their L2 latency
    float ev[8][4];
#pragma unroll
    for (int j = 0; j < 8; ++j)
#pragma unroll
      for (int r = 0; r < 4; ++r)
        ev[j][r] = E[(size_t)tokc[r] * HID + wave * 128 + j * 16 + nn];

    f32x4 acc[8];
#pragma unroll
    for (int j = 0; j < 8; ++j) acc[j] = f32x4{0.f, 0.f, 0.f, 0.f};

    if (t > 0) {
#pragma unroll
      for (int kt = 0; kt < 16; ++kt) {
        const bf16x8 a = __builtin_bit_cast(bf16x8,
            *(const uint4*)&hbuf[nn * HSTR + kt * 32 + q * 8]);
        const bf16x8 b6 = __builtin_bit_cast(bf16x8, lw0[kt * 64]);
        const bf16x8 b7 = __builtin_bit_cast(bf16x8, lw1[kt * 64]);
        acc[0] = __builtin_amdgcn_mfma_f32_16x16x32_bf16(a, wreg[0][kt], acc[0], 0, 0, 0);
        acc[1] = __builtin_amdgcn_mfma_f32_16x16x32_bf16(a, wreg[1][kt], acc[1], 0, 0, 0);
        acc[2] = __builtin_amdgcn_mfma_f32_16x16x32_bf16(a, wreg[2][kt], acc[2], 0, 0, 0);
        acc[3] = __builtin_amdgcn_mfma_f32_16x16x32_bf16(a, wreg[3][kt], acc[3], 0, 0, 0);
        acc[4] = __builtin_amdgcn_mfma_f32_16x16x32_bf16(a, wreg[4][kt], acc[4], 0, 0, 0);
        acc[5] = __builtin_amdgcn_mfma_f32_16x16x32_bf16(a, wreg[5][kt], acc[5], 0, 0, 0);
        acc[6] = __builtin_amdgcn_mfma_f32_16x16x32_bf16(a, b6,          acc[6], 0, 0, 0);
        acc[7] = __builtin_amdgcn_mfma_f32_16x16x32_bf16(a, b7,          acc[7], 0, 0, 0);
      }
    }
    __syncthreads();   // hbuf reads done before overwrite

    // epilogue: h = tanh(z + ev); D layout row m=q*4+r, col nn (verified)
#pragma unroll
    for (int j = 0; j < 8; ++j) {
      const int col = wave * 128 + j * 16 + nn;
#pragma unroll
      for (int r = 0; r < 4; ++r) {
        const int m = q * 4 + r;
        const uint16_t hb = f2bf(fast_tanh(acc[j][r] + ev[j][r]));
        hbuf[m * HSTR + col] = hb;
        Hall[((size_t)(r0 + m) * SEQ + t) * HID + col] = hb;
      }
    }
    __syncthreads();   // hbuf writes published for next step's reads

#pragma unroll
    for (int r = 0; r < 4; ++r) tokc[r] = tokn[r];
  }
}

// Y[b,s,:] = h_{b,s} @ W_ho + b_o over all 131072 rows — fully parallel.
__global__ __launch_bounds__(256)
void ygemm_kernel(const uint16_t* __restrict__ Hall,
                  const uint4* __restrict__ Wf,
                  const float* __restrict__ b_o,
                  float* __restrict__ out) {
  const int tid = threadIdx.x;
  const int wave = tid >> 6, lane = tid & 63;
  const int q = lane >> 4, nn = lane & 15;
  const size_t row0 = (size_t)blockIdx.x * 64 + (size_t)wave * 16;
  f32x4 acc[8];
#pragma unroll
  for (int i = 0; i < 8; ++i) acc[i] = f32x4{0.f, 0.f, 0.f, 0.f};
  const uint16_t* ha = Hall + (row0 + nn) * HID + q * 8;
  const uint4* wb = Wf + (size_t)(32 * 16) * 64 + lane;   // W_ho fragments: nt 32..39
#pragma unroll 4
  for (int kt = 0; kt < 16; ++kt) {
    const bf16x8 a = __builtin_bit_cast(bf16x8, *(const uint4*)(ha + kt * 32));
#pragma unroll
    for (int nt = 0; nt < 8; ++nt) {
      const bf16x8 b = __builtin_bit_cast(bf16x8, wb[(size_t)(nt * 16 + kt) * 64]);
      acc[nt] = __builtin_amdgcn_mfma_f32_16x16x32_bf16(a, b, acc[nt], 0, 0, 0);
    }
  }
#pragma unroll
  for (int nt = 0; nt < 8; ++nt) {
    const float bo = b_o[nt * 16 + nn];
#pragma unroll
    for (int r = 0; r < 4; ++r)
      out[(row0 + q * 4 + r) * VOCAB + nt * 16 + nn] = acc[nt][r] + bo;
  }
}

__global__ __launch_bounds__(512)
void ht_kernel(const uint16_t* __restrict__ Hall, float* __restrict__ outH) {
  const int i = blockIdx.x * 512 + threadIdx.x;
  const int b = i >> 9, h = i & (HID - 1);
  outH[i] = bf2f(Hall[((size_t)b * SEQ + (SEQ - 1)) * HID + h]);
}

extern "C" void kernel_launch(void* const* d_in, const int* in_sizes, int n_in,
                              void* d_out, int out_size, void* d_ws, size_t ws_size,
                              hipStream_t stream) {
  const int*   x    = (const int*)d_in[0];
  const float* emb  = (const float*)d_in[1];
  const float* W_ih = (const float*)d_in[2];
  const float* b_ih = (const float*)d_in[3];
  const float* W_hh = (const float*)d_in[4];
  const float* b_hh = (const float*)d_in[5];
  const float* W_ho = (const float*)d_in[6];
  const float* b_o  = (const float*)d_in[7];
  float* out = (float*)d_out;

  char* ws = (char*)d_ws;
  float*    E    = (float*)ws;                              // 256 KB
  uint32_t* Wf   = (uint32_t*)(ws + (256 << 10));           // 640 KB
  uint16_t* Hall = (uint16_t*)(ws + (1 << 20));             // 128 MB

  // opt-in to >64 KB dynamic LDS (idempotent; immediate-mode API, capture-safe)
  (void)hipFuncSetAttribute((const void*)rnn_kernel,
                            hipFuncAttributeMaxDynamicSharedMemorySize, SMEM_BYTES);

  eproj_kernel<<<VOCAB / 8, 512, 0, stream>>>(emb, W_ih, b_ih, b_hh, E);
  pack_kernel<<<640, 64, 0, stream>>>(W_hh, W_ho, Wf);
  rnn_kernel<<<16, 256, SMEM_BYTES, stream>>>(x, E, (const uint4*)Wf, Hall);
  ygemm_kernel<<<(BATCH * SEQ) / 64, 256, 0, stream>>>(Hall, (const uint4*)Wf, b_o, out);
  ht_kernel<<<BATCH * HID / 512, 512, 0, stream>>>(Hall, out + (size_t)BATCH * SEQ * VOCAB);
}

// Round 6
// 1851.606 us; speedup vs baseline: 1.7969x; 1.0286x over previous
//
#include <hip/hip_runtime.h>
#include <cstdint>
#include <cstddef>

#define BATCH 256
#define SEQ   512
#define HID   512
#define VOCAB 128

#define BT    16               // batch rows per block
#define HSTR  520              // h-buffer row stride in shorts (1040 B, 16B-aligned rows)
#define LWF_BYTES  131072      // 8 strips * 16 frags * 1024 B
#define HBUF_BYTES (BT * HSTR * 2)            // 16640
#define SMEM_BYTES (LWF_BYTES + HBUF_BYTES)   // 147712 <= 160K

typedef __attribute__((ext_vector_type(8))) short bf16x8;
typedef __attribute__((ext_vector_type(4))) float f32x4;

static __device__ __forceinline__ uint16_t f2bf(float f) {
  uint32_t x = __float_as_uint(f);
  return (uint16_t)((x + 0x7fffu + ((x >> 16) & 1u)) >> 16);
}
static __device__ __forceinline__ float bf2f(uint16_t u) {
  return __uint_as_float(((uint32_t)u) << 16);
}
// tanh(z) = 1 - 2/(e^{2z}+1); saturates correctly at +/-inf
static __device__ __forceinline__ float fast_tanh(float z) {
  float e = __expf(2.f * z);
  return 1.f - 2.f * __builtin_amdgcn_rcpf(e + 1.f);
}

// E[v][j] = sum_k emb[v][k]*W_ih[k][j] + b_ih[j] + b_hh[j]
__global__ __launch_bounds__(512) void eproj_kernel(const float* __restrict__ emb,
                                                    const float* __restrict__ W_ih,
                                                    const float* __restrict__ b_ih,
                                                    const float* __restrict__ b_hh,
                                                    float* __restrict__ E) {
  __shared__ float es[8][64];
  const int j = threadIdx.x;
  const int v0 = blockIdx.x * 8;
  float acc[8];
#pragma unroll
  for (int v = 0; v < 8; ++v) acc[v] = 0.f;
  for (int k0 = 0; k0 < HID; k0 += 64) {
    __syncthreads();
    es[j >> 6][j & 63] = emb[(size_t)(v0 + (j >> 6)) * HID + k0 + (j & 63)];
    __syncthreads();
#pragma unroll 8
    for (int kk = 0; kk < 64; ++kk) {
      const float w = W_ih[(size_t)(k0 + kk) * HID + j];
#pragma unroll
      for (int v = 0; v < 8; ++v) acc[v] += es[v][kk] * w;
    }
  }
  const float bias = b_ih[j] + b_hh[j];
#pragma unroll
  for (int v = 0; v < 8; ++v) E[(size_t)(v0 + v) * HID + j] = acc[v] + bias;
}

// Pack [W_hh | W_ho] (512 x 640) into bf16 MFMA B-fragments (layout verified r1-r5).
// Fragment f = nt*16+kt: lane l holds 8 bf16 = B[k = kt*32 + (l>>4)*8 + i][n = nt*16 + (l&15)]
__global__ void pack_kernel(const float* __restrict__ W_hh,
                            const float* __restrict__ W_ho,
                            uint32_t* __restrict__ Wf) {
  const int f = blockIdx.x;            // 0..639
  const int nt = f >> 4, kt = f & 15;
  const int lane = threadIdx.x;
  const int q = lane >> 4, nn = lane & 15;
  const int n = nt * 16 + nn;
  const int k0 = kt * 32 + q * 8;
  uint32_t w[4];
#pragma unroll
  for (int p = 0; p < 4; ++p) {
    const int k = k0 + 2 * p;
    float f0, f1;
    if (n < HID) { f0 = W_hh[(size_t)k * HID + n];           f1 = W_hh[(size_t)(k + 1) * HID + n]; }
    else         { f0 = W_ho[(size_t)k * VOCAB + (n - HID)]; f1 = W_ho[(size_t)(k + 1) * VOCAB + (n - HID)]; }
    w[p] = (uint32_t)f2bf(f0) | ((uint32_t)f2bf(f1) << 16);
  }
  uint4 val; val.x = w[0]; val.y = w[1]; val.z = w[2]; val.w = w[3];
  ((uint4*)Wf)[(size_t)f * 64 + lane] = val;
}

// Recurrence: h_t = tanh(E[x_t] + h_{t-1} @ W_hh), y deferred to ygemm.
// 16 blocks x 256 threads (4 waves, 1 wave/SIMD -> 512 regs/wave = 256 V + 256 A).
// Wave w owns n-tiles w*8..w*8+7: 4 strips AGPR ("+a", exactly 256 — file-feasible),
// 2 strips VGPR ("+v", 128; ~128 VGPRs left for working set), 2 strips LDS.
// Raw barriers: no vmcnt(0) drain -> Hall stores pipeline across steps.
__global__ __launch_bounds__(256, 1)
void rnn_kernel(const int* __restrict__ x,
                const float* __restrict__ E,
                const uint4* __restrict__ Wf,
                uint16_t* __restrict__ Hall) {
  extern __shared__ char smem[];
  uint4*    lwf  = (uint4*)smem;                    // 8 strips = 128 KB
  uint16_t* hbuf = (uint16_t*)(smem + LWF_BYTES);   // [BT][HSTR]

  const int tid = threadIdx.x;
  const int wave = tid >> 6, lane = tid & 63;
  const int q = lane >> 4, nn = lane & 15;
  const int r0 = blockIdx.x * BT;

  // stage the 8 LDS strips: strip s = n-tile (s>>1)*8 + 6 + (s&1)
  for (int i = tid; i < 8192; i += 256) {
    const int s = i >> 10, kt = (i >> 6) & 15, ln = i & 63;
    const int nt = (s >> 1) * 8 + 6 + (s & 1);
    lwf[i] = Wf[(size_t)(nt * 16 + kt) * 64 + ln];
  }

  // 4 strips in AGPRs (256 regs — exact file capacity)
  bf16x8 areg[4][16];
  // 2 strips in VGPRs (128 regs)
  bf16x8 vreg[2][16];
  {
    const uint4* wb = Wf + lane;
#pragma unroll
    for (int j = 0; j < 4; ++j)
#pragma unroll
      for (int kt = 0; kt < 16; ++kt)
        areg[j][kt] = __builtin_bit_cast(bf16x8, wb[(size_t)((wave * 8 + j) * 16 + kt) * 64]);
#pragma unroll
    for (int j = 0; j < 2; ++j)
#pragma unroll
      for (int kt = 0; kt < 16; ++kt)
        vreg[j][kt] = __builtin_bit_cast(bf16x8, wb[(size_t)((wave * 8 + 4 + j) * 16 + kt) * 64]);
  }
#pragma unroll
  for (int j = 0; j < 4; ++j)
#pragma unroll
    for (int kt = 0; kt < 16; ++kt)
      asm volatile("" : "+a"(areg[j][kt]));
#pragma unroll
  for (int j = 0; j < 2; ++j)
#pragma unroll
    for (int kt = 0; kt < 16; ++kt)
      asm volatile("" : "+v"(vreg[j][kt]));

  const uint4* lw0 = lwf + (size_t)((wave * 2 + 0) * 16) * 64 + lane;
  const uint4* lw1 = lwf + (size_t)((wave * 2 + 1) * 16) * 64 + lane;

  __syncthreads();   // staging done (full sync: needs lgkm drain of ds_writes)

  // token prefetch for t=0
  int tokc[4];
#pragma unroll
  for (int r = 0; r < 4; ++r) tokc[r] = x[(size_t)(r0 + q * 4 + r) * SEQ + 0];

  for (int t = 0; t < SEQ; ++t) {
    // next step's tokens (independent; issued early)
    int tokn[4];
    const int tn = (t + 1 < SEQ) ? t + 1 : t;
#pragma unroll
    for (int r = 0; r < 4; ++r) tokn[r] = x[(size_t)(r0 + q * 4 + r) * SEQ + tn];

    // E rows for this step's epilogue — K-loop hides their L2 latency
    float ev[8][4];
#pragma unroll
    for (int j = 0; j < 8; ++j)
#pragma unroll
      for (int r = 0; r < 4; ++r)
        ev[j][r] = E[(size_t)tokc[r] * HID + wave * 128 + j * 16 + nn];

    f32x4 acc[8];
#pragma unroll
    for (int j = 0; j < 8; ++j) acc[j] = f32x4{0.f, 0.f, 0.f, 0.f};

    if (t > 0) {
#pragma unroll
      for (int kt = 0; kt < 16; ++kt) {
        const bf16x8 a = __builtin_bit_cast(bf16x8,
            *(const uint4*)&hbuf[nn * HSTR + kt * 32 + q * 8]);
        const bf16x8 b6 = __builtin_bit_cast(bf16x8, lw0[kt * 64]);
        const bf16x8 b7 = __builtin_bit_cast(bf16x8, lw1[kt * 64]);
        acc[0] = __builtin_amdgcn_mfma_f32_16x16x32_bf16(a, areg[0][kt], acc[0], 0, 0, 0);
        acc[1] = __builtin_amdgcn_mfma_f32_16x16x32_bf16(a, areg[1][kt], acc[1], 0, 0, 0);
        acc[2] = __builtin_amdgcn_mfma_f32_16x16x32_bf16(a, areg[2][kt], acc[2], 0, 0, 0);
        acc[3] = __builtin_amdgcn_mfma_f32_16x16x32_bf16(a, areg[3][kt], acc[3], 0, 0, 0);
        acc[4] = __builtin_amdgcn_mfma_f32_16x16x32_bf16(a, vreg[0][kt], acc[4], 0, 0, 0);
        acc[5] = __builtin_amdgcn_mfma_f32_16x16x32_bf16(a, vreg[1][kt], acc[5], 0, 0, 0);
        acc[6] = __builtin_amdgcn_mfma_f32_16x16x32_bf16(a, b6,          acc[6], 0, 0, 0);
        acc[7] = __builtin_amdgcn_mfma_f32_16x16x32_bf16(a, b7,          acc[7], 0, 0, 0);
      }
    }
    // read->write barrier. A-reads were consumed at MFMA issue, so no waitcnt
    // needed; "memory" stops the compiler moving ds ops across it.
    asm volatile("s_barrier" ::: "memory");

    // epilogue: h = tanh(z + ev); D layout row m=q*4+r, col nn (verified)
#pragma unroll
    for (int j = 0; j < 8; ++j) {
      const int col = wave * 128 + j * 16 + nn;
#pragma unroll
      for (int r = 0; r < 4; ++r) {
        const int m = q * 4 + r;
        const uint16_t hb = f2bf(fast_tanh(acc[j][r] + ev[j][r]));
        hbuf[m * HSTR + col] = hb;
        Hall[((size_t)(r0 + m) * SEQ + t) * HID + col] = hb;
      }
    }
    // write-publish barrier: drain only LDS (lgkm), NOT the Hall global stores.
    asm volatile("s_waitcnt lgkmcnt(0)\n\ts_barrier" ::: "memory");

#pragma unroll
    for (int r = 0; r < 4; ++r) tokc[r] = tokn[r];
  }
}

// Y[b,s,:] = h_{b,s} @ W_ho + b_o over all 131072 rows — fully parallel.
__global__ __launch_bounds__(256)
void ygemm_kernel(const uint16_t* __restrict__ Hall,
                  const uint4* __restrict__ Wf,
                  const float* __restrict__ b_o,
                  float* __restrict__ out) {
  const int tid = threadIdx.x;
  const int wave = tid >> 6, lane = tid & 63;
  const int q = lane >> 4, nn = lane & 15;
  const size_t row0 = (size_t)blockIdx.x * 64 + (size_t)wave * 16;
  f32x4 acc[8];
#pragma unroll
  for (int i = 0; i < 8; ++i) acc[i] = f32x4{0.f, 0.f, 0.f, 0.f};
  const uint16_t* ha = Hall + (row0 + nn) * HID + q * 8;
  const uint4* wb = Wf + (size_t)(32 * 16) * 64 + lane;   // W_ho fragments: nt 32..39
#pragma unroll 4
  for (int kt = 0; kt < 16; ++kt) {
    const bf16x8 a = __builtin_bit_cast(bf16x8, *(const uint4*)(ha + kt * 32));
#pragma unroll
    for (int nt = 0; nt < 8; ++nt) {
      const bf16x8 b = __builtin_bit_cast(bf16x8, wb[(size_t)(nt * 16 + kt) * 64]);
      acc[nt] = __builtin_amdgcn_mfma_f32_16x16x32_bf16(a, b, acc[nt], 0, 0, 0);
    }
  }
#pragma unroll
  for (int nt = 0; nt < 8; ++nt) {
    const float bo = b_o[nt * 16 + nn];
#pragma unroll
    for (int r = 0; r < 4; ++r)
      out[(row0 + q * 4 + r) * VOCAB + nt * 16 + nn] = acc[nt][r] + bo;
  }
}

__global__ __launch_bounds__(512)
void ht_kernel(const uint16_t* __restrict__ Hall, float* __restrict__ outH) {
  const int i = blockIdx.x * 512 + threadIdx.x;
  const int b = i >> 9, h = i & (HID - 1);
  outH[i] = bf2f(Hall[((size_t)b * SEQ + (SEQ - 1)) * HID + h]);
}

extern "C" void kernel_launch(void* const* d_in, const int* in_sizes, int n_in,
                              void* d_out, int out_size, void* d_ws, size_t ws_size,
                              hipStream_t stream) {
  const int*   x    = (const int*)d_in[0];
  const float* emb  = (const float*)d_in[1];
  const float* W_ih = (const float*)d_in[2];
  const float* b_ih = (const float*)d_in[3];
  const float* W_hh = (const float*)d_in[4];
  const float* b_hh = (const float*)d_in[5];
  const float* W_ho = (const float*)d_in[6];
  const float* b_o  = (const float*)d_in[7];
  float* out = (float*)d_out;

  char* ws = (char*)d_ws;
  float*    E    = (float*)ws;                              // 256 KB
  uint32_t* Wf   = (uint32_t*)(ws + (256 << 10));           // 640 KB
  uint16_t* Hall = (uint16_t*)(ws + (1 << 20));             // 128 MB

  // opt-in to >64 KB dynamic LDS (idempotent; immediate-mode API, capture-safe)
  (void)hipFuncSetAttribute((const void*)rnn_kernel,
                            hipFuncAttributeMaxDynamicSharedMemorySize, SMEM_BYTES);

  eproj_kernel<<<VOCAB / 8, 512, 0, stream>>>(emb, W_ih, b_ih, b_hh, E);
  pack_kernel<<<640, 64, 0, stream>>>(W_hh, W_ho, Wf);
  rnn_kernel<<<16, 256, SMEM_BYTES, stream>>>(x, E, (const uint4*)Wf, Hall);
  ygemm_kernel<<<(BATCH * SEQ) / 64, 256, 0, stream>>>(Hall, (const uint4*)Wf, b_o, out);
  ht_kernel<<<BATCH * HID / 512, 512, 0, stream>>>(Hall, out + (size_t)BATCH * SEQ * VOCAB);
}

// Round 7
// 885.457 us; speedup vs baseline: 3.7575x; 2.0911x over previous
//
#include <hip/hip_runtime.h>
#include <cstdint>
#include <cstddef>

#define BATCH 256
#define SEQ   512
#define HID   512
#define VOCAB 128

#define BT     16              // batch rows per block
#define HSTRB  528             // h-buffer row stride in BYTES (512 + 16, 16B-aligned)

typedef __attribute__((ext_vector_type(4))) int   i32x4;
typedef __attribute__((ext_vector_type(4))) float f32x4;

// tanh(z) = 1 - 2/(e^{2z}+1); saturates correctly at +/-inf
static __device__ __forceinline__ float fast_tanh(float z) {
  float e = __expf(2.f * z);
  return 1.f - 2.f * __builtin_amdgcn_rcpf(e + 1.f);
}

// ---- abs-max reduction (for quantization scales) ----
__global__ void maxred_kernel(const float* __restrict__ src, int n,
                              unsigned int* __restrict__ dst) {
  float m = 0.f;
  for (int i = blockIdx.x * blockDim.x + threadIdx.x; i < n; i += gridDim.x * blockDim.x)
    m = fmaxf(m, fabsf(src[i]));
#pragma unroll
  for (int off = 32; off; off >>= 1)
    m = fmaxf(m, __shfl_down(m, off));
  if ((threadIdx.x & 63) == 0) atomicMax(dst, __float_as_uint(m));
}

// E[v][j] = sum_k emb[v][k]*W_ih[k][j] + b_ih[j] + b_hh[j]
__global__ __launch_bounds__(512) void eproj_kernel(const float* __restrict__ emb,
                                                    const float* __restrict__ W_ih,
                                                    const float* __restrict__ b_ih,
                                                    const float* __restrict__ b_hh,
                                                    float* __restrict__ E) {
  __shared__ float es[8][64];
  const int j = threadIdx.x;
  const int v0 = blockIdx.x * 8;
  float acc[8];
#pragma unroll
  for (int v = 0; v < 8; ++v) acc[v] = 0.f;
  for (int k0 = 0; k0 < HID; k0 += 64) {
    __syncthreads();
    es[j >> 6][j & 63] = emb[(size_t)(v0 + (j >> 6)) * HID + k0 + (j & 63)];
    __syncthreads();
#pragma unroll 8
    for (int kk = 0; kk < 64; ++kk) {
      const float w = W_ih[(size_t)(k0 + kk) * HID + j];
#pragma unroll
      for (int v = 0; v < 8; ++v) acc[v] += es[v][kk] * w;
    }
  }
  const float bias = b_ih[j] + b_hh[j];
#pragma unroll
  for (int v = 0; v < 8; ++v) E[(size_t)(v0 + v) * HID + j] = acc[v] + bias;
}

// Pack [W_hh | W_ho] (512 x 640) into i8 MFMA B-fragments for 16x16x64.
// Fragment f = nt*8+kt8: lane l holds 16 i8 = B[k = kt8*64 + (l>>4)*16 + i][n = nt*16 + (l&15)]
// (contiguous per-lane k-extension, extrapolated from the r1-verified bf16 rule)
__global__ void pack8_kernel(const float* __restrict__ W_hh,
                             const float* __restrict__ W_ho,
                             const float* __restrict__ sc,   // sc[0]=max|W_hh|, sc[1]=max|W_ho|
                             uint4* __restrict__ Wf8) {
  const int f = blockIdx.x;            // 0..319 (40 nt * 8 kt8)
  const int nt = f >> 3, kt8 = f & 7;
  const int lane = threadIdx.x;
  const int q = lane >> 4, nn = lane & 15;
  const int n = nt * 16 + nn;
  const float inv = 127.f / ((nt < 32) ? sc[0] : sc[1]);
  union { int8_t b[16]; uint4 u; } val;
#pragma unroll
  for (int i = 0; i < 16; ++i) {
    const int k = kt8 * 64 + q * 16 + i;
    const float w = (n < HID) ? W_hh[(size_t)k * HID + n]
                              : W_ho[(size_t)k * VOCAB + (n - HID)];
    val.b[i] = (int8_t)__float2int_rn(w * inv);
  }
  Wf8[(size_t)f * 64 + lane] = val.u;
}

// Recurrence: h_t = tanh(E[x_t] + h_{t-1} @ W_hh), all-i8 MFMA.
// 16 blocks x 512 threads (8 waves, 2/SIMD). Wave w owns n-tiles w*4..w*4+3;
// ALL weights register-resident: 2 strips AGPR + 2 strips VGPR = 128 regs/wave.
// h kept as i8 in LDS (A-layout) + streamed to Hall (i8). hT written f32 at t=511.
__global__ __launch_bounds__(512, 2)
void rnn_kernel(const int* __restrict__ x,
                const float* __restrict__ E,
                const uint4* __restrict__ Wf8,
                const float* __restrict__ sc,
                int8_t* __restrict__ Hall,
                float* __restrict__ outH) {
  __shared__ __align__(16) int8_t hbuf[BT][HSTRB];   // 8448 B

  const int tid = threadIdx.x;
  const int wave = tid >> 6, lane = tid & 63;
  const int q = lane >> 4, nn = lane & 15;
  const int r0 = blockIdx.x * BT;
  const float f = sc[0] * (1.f / (127.f * 127.f));   // s_w/127, uniform

  // 4 weight strips per wave (nt = wave*4+j): j<2 in AGPR, j>=2 in VGPR; pinned.
  i32x4 wa[2][8], wv[2][8];
  {
    const uint4* wb = Wf8 + lane;
#pragma unroll
    for (int j = 0; j < 2; ++j)
#pragma unroll
      for (int kt = 0; kt < 8; ++kt)
        wa[j][kt] = __builtin_bit_cast(i32x4, wb[(size_t)((wave * 4 + j) * 8 + kt) * 64]);
#pragma unroll
    for (int j = 0; j < 2; ++j)
#pragma unroll
      for (int kt = 0; kt < 8; ++kt)
        wv[j][kt] = __builtin_bit_cast(i32x4, wb[(size_t)((wave * 4 + 2 + j) * 8 + kt) * 64]);
  }
#pragma unroll
  for (int j = 0; j < 2; ++j)
#pragma unroll
    for (int kt = 0; kt < 8; ++kt)
      asm volatile("" : "+a"(wa[j][kt]));
#pragma unroll
  for (int j = 0; j < 2; ++j)
#pragma unroll
    for (int kt = 0; kt < 8; ++kt)
      asm volatile("" : "+v"(wv[j][kt]));

  // token prefetch for t=0
  int tokc[4];
#pragma unroll
  for (int r = 0; r < 4; ++r) tokc[r] = x[(size_t)(r0 + q * 4 + r) * SEQ + 0];

  for (int t = 0; t < SEQ; ++t) {
    int tokn[4];
    const int tn = (t + 1 < SEQ) ? t + 1 : t;
#pragma unroll
    for (int r = 0; r < 4; ++r) tokn[r] = x[(size_t)(r0 + q * 4 + r) * SEQ + tn];

    // E rows for this step's epilogue (K-loop hides the gather latency)
    float ev[4][4];
#pragma unroll
    for (int j = 0; j < 4; ++j)
#pragma unroll
      for (int r = 0; r < 4; ++r)
        ev[j][r] = E[(size_t)tokc[r] * HID + wave * 64 + j * 16 + nn];

    i32x4 acc[4];
#pragma unroll
    for (int j = 0; j < 4; ++j) acc[j] = i32x4{0, 0, 0, 0};

    if (t > 0) {
#pragma unroll
      for (int kt = 0; kt < 8; ++kt) {
        const i32x4 a = *(const i32x4*)&hbuf[nn][kt * 64 + q * 16];
        acc[0] = __builtin_amdgcn_mfma_i32_16x16x64_i8(a, wa[0][kt], acc[0], 0, 0, 0);
        acc[1] = __builtin_amdgcn_mfma_i32_16x16x64_i8(a, wa[1][kt], acc[1], 0, 0, 0);
        acc[2] = __builtin_amdgcn_mfma_i32_16x16x64_i8(a, wv[0][kt], acc[2], 0, 0, 0);
        acc[3] = __builtin_amdgcn_mfma_i32_16x16x64_i8(a, wv[1][kt], acc[3], 0, 0, 0);
      }
    }
    // read->write barrier (A-reads consumed at MFMA issue; no waitcnt needed)
    asm volatile("s_barrier" ::: "memory");

    // epilogue: h = tanh(f*acc + ev); D layout row m=q*4+r, col nn (verified)
#pragma unroll
    for (int j = 0; j < 4; ++j) {
      const int col = wave * 64 + j * 16 + nn;
#pragma unroll
      for (int r = 0; r < 4; ++r) {
        const int m = q * 4 + r;
        const float h = fast_tanh((float)acc[j][r] * f + ev[j][r]);
        const int hi = __float2int_rn(h * 127.f);
        hbuf[m][col] = (int8_t)hi;
        Hall[((size_t)(r0 + m) * SEQ + t) * HID + col] = (int8_t)hi;
        if (t == SEQ - 1) outH[(size_t)(r0 + m) * HID + col] = h;
      }
    }
    // write-publish barrier: drain LDS only, Hall stores keep pipelining
    asm volatile("s_waitcnt lgkmcnt(0)\n\ts_barrier" ::: "memory");

#pragma unroll
    for (int r = 0; r < 4; ++r) tokc[r] = tokn[r];
  }
}

// Y[b,s,:] = (f_hh_h * f_ho) * (h_i8 @ Who_i8) + b_o  — fully parallel, i8 MFMA.
__global__ __launch_bounds__(256)
void ygemm_kernel(const int8_t* __restrict__ Hall,
                  const uint4* __restrict__ Wf8,
                  const float* __restrict__ sc,
                  const float* __restrict__ b_o,
                  float* __restrict__ out) {
  const int tid = threadIdx.x;
  const int wave = tid >> 6, lane = tid & 63;
  const int q = lane >> 4, nn = lane & 15;
  const size_t row0 = (size_t)blockIdx.x * 64 + (size_t)wave * 16;
  const float f = sc[1] * (1.f / (127.f * 127.f));
  i32x4 acc[8];
#pragma unroll
  for (int i = 0; i < 8; ++i) acc[i] = i32x4{0, 0, 0, 0};
  const int8_t* ha = Hall + (row0 + nn) * HID + q * 16;
  const uint4* wb = Wf8 + lane;
#pragma unroll
  for (int kt = 0; kt < 8; ++kt) {
    const i32x4 a = *(const i32x4*)(ha + kt * 64);
#pragma unroll
    for (int nt = 0; nt < 8; ++nt) {
      const i32x4 b = __builtin_bit_cast(i32x4, wb[(size_t)((32 + nt) * 8 + kt) * 64]);
      acc[nt] = __builtin_amdgcn_mfma_i32_16x16x64_i8(a, b, acc[nt], 0, 0, 0);
    }
  }
#pragma unroll
  for (int nt = 0; nt < 8; ++nt) {
    const float bo = b_o[nt * 16 + nn];
#pragma unroll
    for (int r = 0; r < 4; ++r)
      out[(row0 + q * 4 + r) * VOCAB + nt * 16 + nn] = (float)acc[nt][r] * f + bo;
  }
}

extern "C" void kernel_launch(void* const* d_in, const int* in_sizes, int n_in,
                              void* d_out, int out_size, void* d_ws, size_t ws_size,
                              hipStream_t stream) {
  const int*   x    = (const int*)d_in[0];
  const float* emb  = (const float*)d_in[1];
  const float* W_ih = (const float*)d_in[2];
  const float* b_ih = (const float*)d_in[3];
  const float* W_hh = (const float*)d_in[4];
  const float* b_hh = (const float*)d_in[5];
  const float* W_ho = (const float*)d_in[6];
  const float* b_o  = (const float*)d_in[7];
  float* out = (float*)d_out;

  char* ws = (char*)d_ws;
  float*        E      = (float*)ws;                        // 256 KB
  uint4*        Wf8    = (uint4*)(ws + (256 << 10));        // 320 KB (40 nt x 8 x 1 KB)
  unsigned int* scu    = (unsigned int*)(ws + 589824);      // 2 scale slots
  const float*  scf    = (const float*)scu;
  int8_t*       Hall   = (int8_t*)(ws + (1 << 20));         // 64 MB i8

  hipMemsetAsync(scu, 0, 8, stream);   // ws is poisoned 0xAA every launch
  maxred_kernel<<<64, 256, 0, stream>>>(W_hh, HID * HID, scu + 0);
  maxred_kernel<<<16, 256, 0, stream>>>(W_ho, HID * VOCAB, scu + 1);
  eproj_kernel<<<VOCAB / 8, 512, 0, stream>>>(emb, W_ih, b_ih, b_hh, E);
  pack8_kernel<<<320, 64, 0, stream>>>(W_hh, W_ho, scf, Wf8);
  rnn_kernel<<<16, 512, 0, stream>>>(x, E, Wf8, scf, Hall,
                                     out + (size_t)BATCH * SEQ * VOCAB);
  ygemm_kernel<<<(BATCH * SEQ) / 64, 256, 0, stream>>>(Hall, Wf8, scf, b_o, out);
}